// Round 5
// baseline (2645.580 us; speedup 1.0000x reference)
//
#include <hip/hip_runtime.h>

#define N_NODES 50000
#define N_EDGES 800000
#define F 64
#define NBUCK 196        // coarse buckets: dst >> 8
#define CHUNK 6144       // edges per partition workgroup
#define NWG1 ((N_EDGES + CHUNK - 1) / CHUNK)   // 131
#define CAP2 8192        // per-bucket LDS capacity (mean 4082, sigma ~64)

// ---------- A: coarse histogram (LDS-staged; <=196 global atomics per wg) ----------
__global__ __launch_bounds__(256) void coarse_hist(
    const int* __restrict__ dst, int* __restrict__ ccount) {
  __shared__ int h[256];
  int t = threadIdx.x;
  h[t] = 0; __syncthreads();
  for (int i = blockIdx.x * blockDim.x + t; i < N_EDGES; i += gridDim.x * blockDim.x)
    atomicAdd(&h[dst[i] >> 8], 1);
  __syncthreads();
  if (h[t] > 0) atomicAdd(&ccount[t], h[t]);
}

// ---------- B: scan of bucket counts -> cstart (exclusive) + cursor init ----------
__global__ __launch_bounds__(256) void coarse_scan(
    const int* __restrict__ ccount, int* __restrict__ cstart, int* __restrict__ ccursor) {
  __shared__ int s[256];
  int t = threadIdx.x;
  int v = ccount[t];
  s[t] = v; __syncthreads();
  for (int off = 1; off < 256; off <<= 1) {
    int a = (t >= off) ? s[t - off] : 0;
    __syncthreads();
    s[t] += a;
    __syncthreads();
  }
  cstart[t]  = s[t] - v;
  ccursor[t] = s[t] - v;
}

// ---------- C: partition edges into coarse buckets, global writes coalesced ----------
__global__ __launch_bounds__(256) void partition_coarse(
    const int* __restrict__ src, const int* __restrict__ dst,
    int* __restrict__ ccursor, unsigned* __restrict__ ebuf) {
  __shared__ int hist[256], scn[256], gbase[256], lcur[256];
  __shared__ unsigned stage[CHUNK];          // 24 KB
  int t  = threadIdx.x;
  int e0 = blockIdx.x * CHUNK;
  int cnt = N_EDGES - e0; if (cnt > CHUNK) cnt = CHUNK;

  hist[t] = 0; __syncthreads();
  for (int i = t; i < cnt; i += 256) atomicAdd(&hist[dst[e0 + i] >> 8], 1);
  __syncthreads();

  int v = hist[t];
  scn[t] = v; __syncthreads();
  for (int off = 1; off < 256; off <<= 1) {
    int a = (t >= off) ? scn[t - off] : 0;
    __syncthreads();
    scn[t] += a;
    __syncthreads();
  }
  int excl = scn[t] - v;
  scn[t]  = excl;
  lcur[t] = excl;
  if (v > 0) gbase[t] = atomicAdd(&ccursor[t], v);
  __syncthreads();

  for (int i = t; i < cnt; i += 256) {
    int d = dst[e0 + i], s = src[e0 + i];
    int b = d >> 8;
    int p = atomicAdd(&lcur[b], 1);
    stage[p] = ((unsigned)b << 24) | ((unsigned)(d & 255) << 16) | (unsigned)s;
  }
  __syncthreads();

  for (int i = t; i < cnt; i += 256) {
    unsigned e = stage[i];
    int b = e >> 24;
    ebuf[gbase[b] + (i - scn[b])] = e;
  }
}

// ---------- D: per-bucket counting sort; emits edge_src + row_start + deg ----------
__global__ __launch_bounds__(256) void bucket_sort(
    const unsigned* __restrict__ ebuf, const int* __restrict__ cstart,
    int* __restrict__ edge_src, int* __restrict__ row_start, int* __restrict__ deg) {
  __shared__ int lhist[256], lscan[256], lcur[256];
  __shared__ unsigned short srt[CAP2];       // 16 KB
  int b = blockIdx.x, t = threadIdx.x;
  int s0 = cstart[b], s1 = cstart[b + 1];
  int cnt = s1 - s0;

  lhist[t] = 0; __syncthreads();
  for (int i = t; i < cnt; i += 256) atomicAdd(&lhist[(ebuf[s0 + i] >> 16) & 255], 1);
  __syncthreads();

  int v = lhist[t];
  lscan[t] = v; __syncthreads();
  for (int off = 1; off < 256; off <<= 1) {
    int a = (t >= off) ? lscan[t - off] : 0;
    __syncthreads();
    lscan[t] += a;
    __syncthreads();
  }
  lscan[t] -= v;
  lcur[t] = lscan[t];
  __syncthreads();

  for (int i = t; i < cnt; i += 256) {
    unsigned e = ebuf[s0 + i];
    int p = atomicAdd(&lcur[(e >> 16) & 255], 1);
    srt[p] = (unsigned short)(e & 0xFFFFu);
  }
  __syncthreads();

  for (int i = t; i < cnt; i += 256) edge_src[s0 + i] = (int)srt[i];

  int n = b * 256 + t;
  if (n < N_NODES) { row_start[n] = s0 + lscan[t]; deg[n] = v; }
}

// ---------- fused layer: mean-aggregate (regs) + [self||mean] @ W + b ----------
// 256 threads = 4 waves; 32 nodes/block; wave g owns nodes base+g*8 .. +7.
// Phase 1: per node, 4 edge-groups x 16 lanes gather float4 rows; xor-fold leaves
//          every lane holding quad (lane&15) of the mean -> kept in registers.
// Phase 2: out[n][j] = sum_k cat[k]*W[k][j]; cat[k] broadcast via __shfl (lane
//          index is compile-time after unroll), W staged once in LDS.
__global__ __launch_bounds__(256) void sage_layer(
    const float4* __restrict__ feat4,     // [N,16] float4 view of [N,64]
    const int*    __restrict__ row_start,
    const int*    __restrict__ deg,
    const int*    __restrict__ edge_src,  // [E] sorted by dst
    const float*  __restrict__ W,         // [128,64] row-major
    const float*  __restrict__ bias,      // [64]
    float*        __restrict__ out,       // [N,64]
    int do_relu) {
  __shared__ float Ws[128 * 64];          // 32 KB
  int t    = threadIdx.x;
  int g    = t >> 6;       // wave id
  int lane = t & 63;
  int j    = lane;         // output feature in phase 2
  int eg   = lane >> 4;    // edge sub-slot 0..3
  int q    = lane & 15;    // feature quad 0..15
  int base = blockIdx.x * 32;

  // stage W (float4, coalesced): 2048 float4 / 256 thr = 8 each
  {
    const float4* W4 = (const float4*)W;
    float4* Ws4 = (float4*)Ws;
    #pragma unroll
    for (int r = 0; r < 8; ++r) Ws4[r * 256 + t] = W4[r * 256 + t];
  }

  float4 srow[8], mrow[8];
  #pragma unroll
  for (int u = 0; u < 8; ++u) {
    int n = base + g * 8 + u;
    bool ok = (n < N_NODES);
    int start = ok ? row_start[n] : 0;
    int d     = ok ? deg[n] : 0;
    float4 acc = make_float4(0.f, 0.f, 0.f, 0.f);
    #pragma unroll 2
    for (int be = 0; be < d; be += 4) {
      int e = be + eg;
      if (e < d) {
        int s = edge_src[start + e];
        float4 v = feat4[(size_t)s * 16 + q];
        acc.x += v.x; acc.y += v.y; acc.z += v.z; acc.w += v.w;
      }
    }
    acc.x += __shfl_xor(acc.x, 16); acc.y += __shfl_xor(acc.y, 16);
    acc.z += __shfl_xor(acc.z, 16); acc.w += __shfl_xor(acc.w, 16);
    acc.x += __shfl_xor(acc.x, 32); acc.y += __shfl_xor(acc.y, 32);
    acc.z += __shfl_xor(acc.z, 32); acc.w += __shfl_xor(acc.w, 32);
    float inv = (d > 0) ? 1.0f / (float)d : 0.0f;
    mrow[u] = make_float4(acc.x * inv, acc.y * inv, acc.z * inv, acc.w * inv);
    srow[u] = ok ? feat4[(size_t)n * 16 + q]
                 : make_float4(0.f, 0.f, 0.f, 0.f);
  }
  __syncthreads();   // Ws ready (and all waves done staging)

  float bj = bias[j];
  float acc[8];
  #pragma unroll
  for (int u = 0; u < 8; ++u) acc[u] = bj;

  #pragma unroll
  for (int k4 = 0; k4 < 32; ++k4) {
    float w0 = Ws[(k4 * 4 + 0) * 64 + j];
    float w1 = Ws[(k4 * 4 + 1) * 64 + j];
    float w2 = Ws[(k4 * 4 + 2) * 64 + j];
    float w3 = Ws[(k4 * 4 + 3) * 64 + j];
    const int lsrc = k4 & 15;
    #pragma unroll
    for (int u = 0; u < 8; ++u) {
      float4 rv = (k4 < 16) ? srow[u] : mrow[u];   // static after unroll
      float r0 = __shfl(rv.x, lsrc);
      float r1 = __shfl(rv.y, lsrc);
      float r2 = __shfl(rv.z, lsrc);
      float r3 = __shfl(rv.w, lsrc);
      acc[u] += r0 * w0 + r1 * w1 + r2 * w2 + r3 * w3;
    }
  }

  #pragma unroll
  for (int u = 0; u < 8; ++u) {
    int n = base + g * 8 + u;
    if (n < N_NODES) {
      float v = acc[u];
      if (do_relu) v = fmaxf(v, 0.0f);
      out[(size_t)n * F + j] = v;
    }
  }
}

extern "C" void kernel_launch(void* const* d_in, const int* in_sizes, int n_in,
                              void* d_out, int out_size, void* d_ws, size_t ws_size,
                              hipStream_t stream) {
  const float* x  = (const float*)d_in[0];
  const int*   ei = (const int*)d_in[1];   // [2,E]: row 0 = src, row 1 = dst
  const float* W1 = (const float*)d_in[2];
  const float* b1 = (const float*)d_in[3];
  const float* W2 = (const float*)d_in[4];
  const float* b2 = (const float*)d_in[5];
  float* out = (float*)d_out;

  const int* src = ei;
  const int* dst = ei + N_EDGES;

  // ws layout (int offsets):
  //   ccount@0[256] | cstart@512[260] | ccursor@1024[256] | deg@1536[50048] |
  //   row_start@51584[50048] | edge_src@101632[800000] | ebuf@901632[800000] |
  //   h1@1701632[N*64]   -> total 4,901,632 ints = 19.6 MB
  int* wsi       = (int*)d_ws;
  int* ccount    = wsi;
  int* cstart    = wsi + 512;
  int* ccursor   = wsi + 1024;
  int* deg       = wsi + 1536;
  int* row_start = wsi + 51584;
  int* edge_src  = wsi + 101632;
  unsigned* ebuf = (unsigned*)(wsi + 901632);
  float* h1      = (float*)(wsi + 1701632);

  hipMemsetAsync(ccount, 0, 256 * sizeof(int), stream);

  dim3 blk(256);
  coarse_hist<<<256, blk, 0, stream>>>(dst, ccount);
  coarse_scan<<<1, blk, 0, stream>>>(ccount, cstart, ccursor);
  partition_coarse<<<NWG1, blk, 0, stream>>>(src, dst, ccursor, ebuf);
  bucket_sort<<<NBUCK, blk, 0, stream>>>(ebuf, cstart, edge_src, row_start, deg);

  dim3 grd_lay((N_NODES + 31) / 32);   // 1563
  sage_layer<<<grd_lay, blk, 0, stream>>>(
      (const float4*)x, row_start, deg, edge_src, W1, b1, h1, 1);
  sage_layer<<<grd_lay, blk, 0, stream>>>(
      (const float4*)h1, row_start, deg, edge_src, W2, b2, out, 0);
}

// Round 6
// 330.087 us; speedup vs baseline: 8.0148x; 8.0148x over previous
//
#include <hip/hip_runtime.h>

#define N_NODES 50000
#define N_EDGES 800000
#define F 64
#define NBUCK 196        // coarse buckets: dst >> 8
#define CHUNK 6144       // edges per partition workgroup
#define NWG1 ((N_EDGES + CHUNK - 1) / CHUNK)   // 131
#define CAP2 8192        // per-bucket LDS capacity (mean 4082, sigma ~64)

// ---------- A: coarse histogram (LDS-staged; <=196 global atomics per wg) ----------
__global__ __launch_bounds__(256) void coarse_hist(
    const int* __restrict__ dst, int* __restrict__ ccount) {
  __shared__ int h[256];
  int t = threadIdx.x;
  h[t] = 0; __syncthreads();
  for (int i = blockIdx.x * blockDim.x + t; i < N_EDGES; i += gridDim.x * blockDim.x)
    atomicAdd(&h[dst[i] >> 8], 1);
  __syncthreads();
  if (h[t] > 0) atomicAdd(&ccount[t], h[t]);
}

// ---------- B: scan of bucket counts -> cstart (exclusive) + cursor init ----------
__global__ __launch_bounds__(256) void coarse_scan(
    const int* __restrict__ ccount, int* __restrict__ cstart, int* __restrict__ ccursor) {
  __shared__ int s[256];
  int t = threadIdx.x;
  int v = ccount[t];
  s[t] = v; __syncthreads();
  for (int off = 1; off < 256; off <<= 1) {
    int a = (t >= off) ? s[t - off] : 0;
    __syncthreads();
    s[t] += a;
    __syncthreads();
  }
  cstart[t]  = s[t] - v;
  ccursor[t] = s[t] - v;
}

// ---------- C: partition edges into coarse buckets, global writes coalesced ----------
__global__ __launch_bounds__(256) void partition_coarse(
    const int* __restrict__ src, const int* __restrict__ dst,
    int* __restrict__ ccursor, unsigned* __restrict__ ebuf) {
  __shared__ int hist[256], scn[256], gbase[256], lcur[256];
  __shared__ unsigned stage[CHUNK];          // 24 KB
  int t  = threadIdx.x;
  int e0 = blockIdx.x * CHUNK;
  int cnt = N_EDGES - e0; if (cnt > CHUNK) cnt = CHUNK;

  hist[t] = 0; __syncthreads();
  for (int i = t; i < cnt; i += 256) atomicAdd(&hist[dst[e0 + i] >> 8], 1);
  __syncthreads();

  int v = hist[t];
  scn[t] = v; __syncthreads();
  for (int off = 1; off < 256; off <<= 1) {
    int a = (t >= off) ? scn[t - off] : 0;
    __syncthreads();
    scn[t] += a;
    __syncthreads();
  }
  int excl = scn[t] - v;
  scn[t]  = excl;
  lcur[t] = excl;
  if (v > 0) gbase[t] = atomicAdd(&ccursor[t], v);
  __syncthreads();

  for (int i = t; i < cnt; i += 256) {
    int d = dst[e0 + i], s = src[e0 + i];
    int b = d >> 8;
    int p = atomicAdd(&lcur[b], 1);
    stage[p] = ((unsigned)b << 24) | ((unsigned)(d & 255) << 16) | (unsigned)s;
  }
  __syncthreads();

  for (int i = t; i < cnt; i += 256) {
    unsigned e = stage[i];
    int b = e >> 24;
    ebuf[gbase[b] + (i - scn[b])] = e;
  }
}

// ---------- D: per-bucket counting sort; emits edge_src + row_start + deg ----------
__global__ __launch_bounds__(256) void bucket_sort(
    const unsigned* __restrict__ ebuf, const int* __restrict__ cstart,
    int* __restrict__ edge_src, int* __restrict__ row_start, int* __restrict__ deg) {
  __shared__ int lhist[256], lscan[256], lcur[256];
  __shared__ unsigned short srt[CAP2];       // 16 KB
  int b = blockIdx.x, t = threadIdx.x;
  int s0 = cstart[b], s1 = cstart[b + 1];
  int cnt = s1 - s0;

  lhist[t] = 0; __syncthreads();
  for (int i = t; i < cnt; i += 256) atomicAdd(&lhist[(ebuf[s0 + i] >> 16) & 255], 1);
  __syncthreads();

  int v = lhist[t];
  lscan[t] = v; __syncthreads();
  for (int off = 1; off < 256; off <<= 1) {
    int a = (t >= off) ? lscan[t - off] : 0;
    __syncthreads();
    lscan[t] += a;
    __syncthreads();
  }
  lscan[t] -= v;
  lcur[t] = lscan[t];
  __syncthreads();

  for (int i = t; i < cnt; i += 256) {
    unsigned e = ebuf[s0 + i];
    int p = atomicAdd(&lcur[(e >> 16) & 255], 1);
    srt[p] = (unsigned short)(e & 0xFFFFu);
  }
  __syncthreads();

  for (int i = t; i < cnt; i += 256) edge_src[s0 + i] = (int)srt[i];

  int n = b * 256 + t;
  if (n < N_NODES) { row_start[n] = s0 + lscan[t]; deg[n] = v; }
}

// ---------- fused layer: mean-aggregate -> LDS rows -> [self||mean] @ W + b ----------
// 256 threads = 4 waves; 32 nodes/block; wave g owns nodes base+g*8..+7 in BOTH
// phases, so row[] carries no cross-wave dependency (single barrier, for Ws only).
// Phase 1 (per node): 4 edge-groups x 16 lanes gather float4 rows; xor-fold; lanes
//   0-15 store the mean quads, lanes 16-31 store the self quads -> row[i][0:128].
// Phase 2: R4's measured-safe linear loop (r[8] b128 broadcast + Ws b32).
__global__ __launch_bounds__(256) void sage_layer(
    const float4* __restrict__ feat4,     // [N,16] float4 view of [N,64]
    const int*    __restrict__ row_start,
    const int*    __restrict__ deg,
    const int*    __restrict__ edge_src,  // [E] sorted by dst
    const float*  __restrict__ W,         // [128,64] row-major
    const float*  __restrict__ bias,      // [64]
    float*        __restrict__ out,       // [N,64]
    int do_relu) {
  __shared__ float Ws[128 * 64];          // 32 KB
  __shared__ float row[32][128];          // 16 KB
  int t    = threadIdx.x;
  int g    = t >> 6;       // wave id
  int lane = t & 63;
  int j    = lane;         // output feature in phase 2
  int eg   = lane >> 4;    // edge sub-slot 0..3
  int q    = lane & 15;    // feature quad 0..15
  int base = blockIdx.x * 32;

  // stage W (float4, coalesced); barrier comes after phase 1 so these stores
  // complete behind the gather latency
  {
    const float4* W4 = (const float4*)W;
    float4* Ws4 = (float4*)Ws;
    #pragma unroll
    for (int r = 0; r < 8; ++r) Ws4[r * 256 + t] = W4[r * 256 + t];
  }

  // phase 1: aggregate this wave's 8 nodes into LDS rows (results leave
  // registers immediately -> no pressure; unroll 2 for gather MLP)
  #pragma unroll 2
  for (int u = 0; u < 8; ++u) {
    int i = g * 8 + u;
    int n = base + i;
    if (n < N_NODES) {
      int start = row_start[n];
      int d     = deg[n];
      float4 acc = make_float4(0.f, 0.f, 0.f, 0.f);
      #pragma unroll 2
      for (int be = 0; be < d; be += 4) {
        int e = be + eg;
        if (e < d) {
          int s = edge_src[start + e];
          float4 v = feat4[(size_t)s * 16 + q];
          acc.x += v.x; acc.y += v.y; acc.z += v.z; acc.w += v.w;
        }
      }
      acc.x += __shfl_xor(acc.x, 16); acc.y += __shfl_xor(acc.y, 16);
      acc.z += __shfl_xor(acc.z, 16); acc.w += __shfl_xor(acc.w, 16);
      acc.x += __shfl_xor(acc.x, 32); acc.y += __shfl_xor(acc.y, 32);
      acc.z += __shfl_xor(acc.z, 32); acc.w += __shfl_xor(acc.w, 32);
      if (lane < 16) {
        float inv = (d > 0) ? 1.0f / (float)d : 0.0f;
        *(float4*)&row[i][64 + q * 4] =
            make_float4(acc.x * inv, acc.y * inv, acc.z * inv, acc.w * inv);
      } else if (lane < 32) {
        *(float4*)&row[i][q * 4] = feat4[(size_t)n * 16 + q];   // self quads
      }
    } else if (lane < 32) {
      // keep LDS defined for the tail block
      float4 z = make_float4(0.f, 0.f, 0.f, 0.f);
      if (lane < 16) *(float4*)&row[i][64 + q * 4] = z;
      else           *(float4*)&row[i][q * 4] = z;
    }
  }
  __syncthreads();   // Ws ready (row[] is wave-local)

  // phase 2: out[n][j] = sum_k row[i][k] * Ws[k][j] + b[j]
  float bj = bias[j];
  float acc[8];
  #pragma unroll
  for (int u = 0; u < 8; ++u) acc[u] = bj;

  #pragma unroll 4
  for (int k4 = 0; k4 < 32; ++k4) {
    float4 r[8];
    #pragma unroll
    for (int u = 0; u < 8; ++u)
      r[u] = *(const float4*)&row[g * 8 + u][k4 * 4];
    #pragma unroll
    for (int kk = 0; kk < 4; ++kk) {
      float w = Ws[(k4 * 4 + kk) * 64 + j];
      #pragma unroll
      for (int u = 0; u < 8; ++u)
        acc[u] += ((const float*)&r[u])[kk] * w;
    }
  }

  #pragma unroll
  for (int u = 0; u < 8; ++u) {
    int n = base + g * 8 + u;
    if (n < N_NODES) {
      float v = acc[u];
      if (do_relu) v = fmaxf(v, 0.0f);
      out[(size_t)n * F + j] = v;
    }
  }
}

extern "C" void kernel_launch(void* const* d_in, const int* in_sizes, int n_in,
                              void* d_out, int out_size, void* d_ws, size_t ws_size,
                              hipStream_t stream) {
  const float* x  = (const float*)d_in[0];
  const int*   ei = (const int*)d_in[1];   // [2,E]: row 0 = src, row 1 = dst
  const float* W1 = (const float*)d_in[2];
  const float* b1 = (const float*)d_in[3];
  const float* W2 = (const float*)d_in[4];
  const float* b2 = (const float*)d_in[5];
  float* out = (float*)d_out;

  const int* src = ei;
  const int* dst = ei + N_EDGES;

  // ws layout (int offsets):
  //   ccount@0[256] | cstart@512[260] | ccursor@1024[256] | deg@1536[50048] |
  //   row_start@51584[50048] | edge_src@101632[800000] | ebuf@901632[800000] |
  //   h1@1701632[N*64]   -> total 4,901,632 ints = 19.6 MB
  int* wsi       = (int*)d_ws;
  int* ccount    = wsi;
  int* cstart    = wsi + 512;
  int* ccursor   = wsi + 1024;
  int* deg       = wsi + 1536;
  int* row_start = wsi + 51584;
  int* edge_src  = wsi + 101632;
  unsigned* ebuf = (unsigned*)(wsi + 901632);
  float* h1      = (float*)(wsi + 1701632);

  hipMemsetAsync(ccount, 0, 256 * sizeof(int), stream);

  dim3 blk(256);
  coarse_hist<<<256, blk, 0, stream>>>(dst, ccount);
  coarse_scan<<<1, blk, 0, stream>>>(ccount, cstart, ccursor);
  partition_coarse<<<NWG1, blk, 0, stream>>>(src, dst, ccursor, ebuf);
  bucket_sort<<<NBUCK, blk, 0, stream>>>(ebuf, cstart, edge_src, row_start, deg);

  dim3 grd_lay((N_NODES + 31) / 32);   // 1563
  sage_layer<<<grd_lay, blk, 0, stream>>>(
      (const float4*)x, row_start, deg, edge_src, W1, b1, h1, 1);
  sage_layer<<<grd_lay, blk, 0, stream>>>(
      (const float4*)h1, row_start, deg, edge_src, W2, b2, out, 0);
}

// Round 7
// 235.322 us; speedup vs baseline: 11.2424x; 1.4027x over previous
//
#include <hip/hip_runtime.h>

#define N_NODES 50000
#define N_EDGES 800000
#define F 64
#define NBUCK 196        // coarse buckets: dst >> 8
#define CHUNK 6144       // edges per partition workgroup
#define NWG1 ((N_EDGES + CHUNK - 1) / CHUNK)   // 131
#define CAP2 8192        // per-bucket LDS capacity (mean 4082, sigma ~64)

// ---------- A: coarse histogram (LDS-staged; <=196 global atomics per wg) ----------
__global__ __launch_bounds__(256) void coarse_hist(
    const int* __restrict__ dst, int* __restrict__ ccount) {
  __shared__ int h[256];
  int t = threadIdx.x;
  h[t] = 0; __syncthreads();
  for (int i = blockIdx.x * blockDim.x + t; i < N_EDGES; i += gridDim.x * blockDim.x)
    atomicAdd(&h[dst[i] >> 8], 1);
  __syncthreads();
  if (h[t] > 0) atomicAdd(&ccount[t], h[t]);
}

// ---------- B: scan of bucket counts -> cstart (exclusive) + cursor init ----------
__global__ __launch_bounds__(256) void coarse_scan(
    const int* __restrict__ ccount, int* __restrict__ cstart, int* __restrict__ ccursor) {
  __shared__ int s[256];
  int t = threadIdx.x;
  int v = ccount[t];
  s[t] = v; __syncthreads();
  for (int off = 1; off < 256; off <<= 1) {
    int a = (t >= off) ? s[t - off] : 0;
    __syncthreads();
    s[t] += a;
    __syncthreads();
  }
  cstart[t]  = s[t] - v;
  ccursor[t] = s[t] - v;
}

// ---------- C: partition edges into coarse buckets, global writes coalesced ----------
__global__ __launch_bounds__(256) void partition_coarse(
    const int* __restrict__ src, const int* __restrict__ dst,
    int* __restrict__ ccursor, unsigned* __restrict__ ebuf) {
  __shared__ int hist[256], scn[256], gbase[256], lcur[256];
  __shared__ unsigned stage[CHUNK];          // 24 KB
  int t  = threadIdx.x;
  int e0 = blockIdx.x * CHUNK;
  int cnt = N_EDGES - e0; if (cnt > CHUNK) cnt = CHUNK;

  hist[t] = 0; __syncthreads();
  for (int i = t; i < cnt; i += 256) atomicAdd(&hist[dst[e0 + i] >> 8], 1);
  __syncthreads();

  int v = hist[t];
  scn[t] = v; __syncthreads();
  for (int off = 1; off < 256; off <<= 1) {
    int a = (t >= off) ? scn[t - off] : 0;
    __syncthreads();
    scn[t] += a;
    __syncthreads();
  }
  int excl = scn[t] - v;
  scn[t]  = excl;
  lcur[t] = excl;
  if (v > 0) gbase[t] = atomicAdd(&ccursor[t], v);
  __syncthreads();

  for (int i = t; i < cnt; i += 256) {
    int d = dst[e0 + i], s = src[e0 + i];
    int b = d >> 8;
    int p = atomicAdd(&lcur[b], 1);
    stage[p] = ((unsigned)b << 24) | ((unsigned)(d & 255) << 16) | (unsigned)s;
  }
  __syncthreads();

  for (int i = t; i < cnt; i += 256) {
    unsigned e = stage[i];
    int b = e >> 24;
    ebuf[gbase[b] + (i - scn[b])] = e;
  }
}

// ---------- D: per-bucket counting sort; emits edge_src + row_start + deg ----------
__global__ __launch_bounds__(256) void bucket_sort(
    const unsigned* __restrict__ ebuf, const int* __restrict__ cstart,
    int* __restrict__ edge_src, int* __restrict__ row_start, int* __restrict__ deg) {
  __shared__ int lhist[256], lscan[256], lcur[256];
  __shared__ unsigned short srt[CAP2];       // 16 KB
  int b = blockIdx.x, t = threadIdx.x;
  int s0 = cstart[b], s1 = cstart[b + 1];
  int cnt = s1 - s0;

  lhist[t] = 0; __syncthreads();
  for (int i = t; i < cnt; i += 256) atomicAdd(&lhist[(ebuf[s0 + i] >> 16) & 255], 1);
  __syncthreads();

  int v = lhist[t];
  lscan[t] = v; __syncthreads();
  for (int off = 1; off < 256; off <<= 1) {
    int a = (t >= off) ? lscan[t - off] : 0;
    __syncthreads();
    lscan[t] += a;
    __syncthreads();
  }
  lscan[t] -= v;
  lcur[t] = lscan[t];
  __syncthreads();

  for (int i = t; i < cnt; i += 256) {
    unsigned e = ebuf[s0 + i];
    int p = atomicAdd(&lcur[(e >> 16) & 255], 1);
    srt[p] = (unsigned short)(e & 0xFFFFu);
  }
  __syncthreads();

  for (int i = t; i < cnt; i += 256) edge_src[s0 + i] = (int)srt[i];

  int n = b * 256 + t;
  if (n < N_NODES) { row_start[n] = s0 + lscan[t]; deg[n] = v; }
}

// ---------- pull-mode mean aggregation (R4 version, unroll 4 for more MLP) ----------
__global__ __launch_bounds__(256) void sage_aggregate(
    const float4* __restrict__ feat4,     // [N,16] float4 view of [N,64]
    const int*    __restrict__ row_start,
    const int*    __restrict__ deg,
    const int*    __restrict__ edge_src,  // [E] sorted by dst
    float4*       __restrict__ mean4) {   // [N,16] float4 view
  int idx  = blockIdx.x * blockDim.x + threadIdx.x;
  int n    = idx >> 6;
  int lane = idx & 63;
  if (n >= N_NODES) return;
  int g = lane >> 4;     // edge sub-slot 0..3
  int q = lane & 15;     // feature quad 0..15
  int start = row_start[n];
  int d     = deg[n];
  float4 acc = make_float4(0.f, 0.f, 0.f, 0.f);
  #pragma unroll 4
  for (int base = 0; base < d; base += 4) {
    int e = base + g;
    if (e < d) {
      int s = edge_src[start + e];
      float4 v = feat4[(size_t)s * 16 + q];
      acc.x += v.x; acc.y += v.y; acc.z += v.z; acc.w += v.w;
    }
  }
  acc.x += __shfl_xor(acc.x, 16); acc.y += __shfl_xor(acc.y, 16);
  acc.z += __shfl_xor(acc.z, 16); acc.w += __shfl_xor(acc.w, 16);
  acc.x += __shfl_xor(acc.x, 32); acc.y += __shfl_xor(acc.y, 32);
  acc.z += __shfl_xor(acc.z, 32); acc.w += __shfl_xor(acc.w, 32);
  if (lane < 16) {
    float inv = (d > 0) ? 1.0f / (float)d : 0.0f;
    acc.x *= inv; acc.y *= inv; acc.z *= inv; acc.w *= inv;
    mean4[(size_t)n * 16 + q] = acc;
  }
}

// ---------- linear via scalar row reads ----------
// Thread (wave g, lane j): 8 nodes per wave, output feature j.
// Row addresses are wave-uniform (readfirstlane on wave id) -> compiler emits
// s_load for xin/mean rows: the scalar pipe feeds the FMA, LDS only carries W
// (1 ds_read_b32 per k, reused by 8 nodes). No row staging, 32 KB LDS.
__global__ __launch_bounds__(256) void sage_linear(
    const float* __restrict__ xin,   // [N,64]
    const float* __restrict__ mean,  // [N,64]
    const float* __restrict__ W,     // [128,64] row-major
    const float* __restrict__ bias,  // [64]
    float*       __restrict__ out,   // [N,64]
    int do_relu) {
  __shared__ float Ws[128 * 64];     // 32 KB
  int t = threadIdx.x;
  int j = t & 63;
  int g = __builtin_amdgcn_readfirstlane(t >> 6);   // wave id, forced SGPR

  {
    const float4* W4 = (const float4*)W;
    float4* Ws4 = (float4*)Ws;
    #pragma unroll
    for (int r = 0; r < 8; ++r) Ws4[r * 256 + t] = W4[r * 256 + t];
  }
  __syncthreads();

  int base = blockIdx.x * 32 + g * 8;               // uniform
  float bj = bias[j];
  float acc[8];
  #pragma unroll
  for (int u = 0; u < 8; ++u) acc[u] = bj;

  int nc[8];                                        // clamped node ids (uniform)
  #pragma unroll
  for (int u = 0; u < 8; ++u) {
    int n = base + u;
    nc[u] = (n < N_NODES) ? n : (N_NODES - 1);
  }

  // self half: k in [0,64)
  #pragma unroll 8
  for (int k = 0; k < 64; ++k) {
    float w = Ws[k * 64 + j];
    #pragma unroll
    for (int u = 0; u < 8; ++u)
      acc[u] += xin[(size_t)nc[u] * 64 + k] * w;    // uniform addr -> s_load
  }
  // mean half: k in [64,128)
  #pragma unroll 8
  for (int k = 0; k < 64; ++k) {
    float w = Ws[(64 + k) * 64 + j];
    #pragma unroll
    for (int u = 0; u < 8; ++u)
      acc[u] += mean[(size_t)nc[u] * 64 + k] * w;   // uniform addr -> s_load
  }

  #pragma unroll
  for (int u = 0; u < 8; ++u) {
    int n = base + u;
    if (n < N_NODES) {
      float v = acc[u];
      if (do_relu) v = fmaxf(v, 0.0f);
      out[(size_t)n * 64 + j] = v;
    }
  }
}

extern "C" void kernel_launch(void* const* d_in, const int* in_sizes, int n_in,
                              void* d_out, int out_size, void* d_ws, size_t ws_size,
                              hipStream_t stream) {
  const float* x  = (const float*)d_in[0];
  const int*   ei = (const int*)d_in[1];   // [2,E]: row 0 = src, row 1 = dst
  const float* W1 = (const float*)d_in[2];
  const float* b1 = (const float*)d_in[3];
  const float* W2 = (const float*)d_in[4];
  const float* b2 = (const float*)d_in[5];
  float* out = (float*)d_out;

  const int* src = ei;
  const int* dst = ei + N_EDGES;

  // ws layout (int offsets) — same as R4:
  //   ccount@0[256] | cstart@512[260] | ccursor@1024[256] | deg@1536[50048] |
  //   row_start@51584[50048] | edge_src@101632[800000] |
  //   ebuf@901632[800000]  (ALIASES mean — ebuf dead before first aggregate) |
  //   mean@901632[N*64] | h1@4101632[N*64]   total 7,301,632 ints = 29.2 MB
  int* wsi       = (int*)d_ws;
  int* ccount    = wsi;
  int* cstart    = wsi + 512;
  int* ccursor   = wsi + 1024;
  int* deg       = wsi + 1536;
  int* row_start = wsi + 51584;
  int* edge_src  = wsi + 101632;
  unsigned* ebuf = (unsigned*)(wsi + 901632);
  float* mean    = (float*)(wsi + 901632);
  float* h1      = (float*)(wsi + 4101632);

  hipMemsetAsync(ccount, 0, 256 * sizeof(int), stream);

  dim3 blk(256);
  coarse_hist<<<256, blk, 0, stream>>>(dst, ccount);
  coarse_scan<<<1, blk, 0, stream>>>(ccount, cstart, ccursor);
  partition_coarse<<<NWG1, blk, 0, stream>>>(src, dst, ccursor, ebuf);
  bucket_sort<<<NBUCK, blk, 0, stream>>>(ebuf, cstart, edge_src, row_start, deg);

  dim3 grd_agg((unsigned)(((size_t)N_NODES * 64 + 255) / 256));  // 12500
  dim3 grd_lin((N_NODES + 31) / 32);                             // 1563

  // Layer 1
  sage_aggregate<<<grd_agg, blk, 0, stream>>>(
      (const float4*)x, row_start, deg, edge_src, (float4*)mean);
  sage_linear<<<grd_lin, blk, 0, stream>>>(x, mean, W1, b1, h1, 1);
  // Layer 2
  sage_aggregate<<<grd_agg, blk, 0, stream>>>(
      (const float4*)h1, row_start, deg, edge_src, (float4*)mean);
  sage_linear<<<grd_lin, blk, 0, stream>>>(h1, mean, W2, b2, out, 0);
}

// Round 8
// 223.535 us; speedup vs baseline: 11.8352x; 1.0527x over previous
//
#include <hip/hip_runtime.h>

#define N_NODES 50000
#define N_EDGES 800000
#define F 64
#define NBUCK 196        // coarse buckets: dst >> 8
#define CHUNK 6144       // edges per partition workgroup
#define NWG1 ((N_EDGES + CHUNK - 1) / CHUNK)   // 131
#define CAP2 8192        // per-bucket LDS capacity (mean 4082, sigma ~64)

typedef __attribute__((ext_vector_type(8))) _Float16 half8;   // 16 B

// ---------- f32 [N,64] -> f16 [N,64] (one half8 per thread) ----------
__global__ __launch_bounds__(256) void to_f16(
    const float4* __restrict__ in, half8* __restrict__ out16) {
  int i = blockIdx.x * blockDim.x + threadIdx.x;   // 0 .. N*64/8
  if (i < N_NODES * F / 8) {
    float4 a = in[i * 2], b = in[i * 2 + 1];
    half8 h;
    h[0] = (_Float16)a.x; h[1] = (_Float16)a.y;
    h[2] = (_Float16)a.z; h[3] = (_Float16)a.w;
    h[4] = (_Float16)b.x; h[5] = (_Float16)b.y;
    h[6] = (_Float16)b.z; h[7] = (_Float16)b.w;
    out16[i] = h;
  }
}

// ---------- A: coarse histogram ----------
__global__ __launch_bounds__(256) void coarse_hist(
    const int* __restrict__ dst, int* __restrict__ ccount) {
  __shared__ int h[256];
  int t = threadIdx.x;
  h[t] = 0; __syncthreads();
  for (int i = blockIdx.x * blockDim.x + t; i < N_EDGES; i += gridDim.x * blockDim.x)
    atomicAdd(&h[dst[i] >> 8], 1);
  __syncthreads();
  if (h[t] > 0) atomicAdd(&ccount[t], h[t]);
}

// ---------- B: scan of bucket counts ----------
__global__ __launch_bounds__(256) void coarse_scan(
    const int* __restrict__ ccount, int* __restrict__ cstart, int* __restrict__ ccursor) {
  __shared__ int s[256];
  int t = threadIdx.x;
  int v = ccount[t];
  s[t] = v; __syncthreads();
  for (int off = 1; off < 256; off <<= 1) {
    int a = (t >= off) ? s[t - off] : 0;
    __syncthreads();
    s[t] += a;
    __syncthreads();
  }
  cstart[t]  = s[t] - v;
  ccursor[t] = s[t] - v;
}

// ---------- C: partition edges into coarse buckets ----------
__global__ __launch_bounds__(256) void partition_coarse(
    const int* __restrict__ src, const int* __restrict__ dst,
    int* __restrict__ ccursor, unsigned* __restrict__ ebuf) {
  __shared__ int hist[256], scn[256], gbase[256], lcur[256];
  __shared__ unsigned stage[CHUNK];          // 24 KB
  int t  = threadIdx.x;
  int e0 = blockIdx.x * CHUNK;
  int cnt = N_EDGES - e0; if (cnt > CHUNK) cnt = CHUNK;

  hist[t] = 0; __syncthreads();
  for (int i = t; i < cnt; i += 256) atomicAdd(&hist[dst[e0 + i] >> 8], 1);
  __syncthreads();

  int v = hist[t];
  scn[t] = v; __syncthreads();
  for (int off = 1; off < 256; off <<= 1) {
    int a = (t >= off) ? scn[t - off] : 0;
    __syncthreads();
    scn[t] += a;
    __syncthreads();
  }
  int excl = scn[t] - v;
  scn[t]  = excl;
  lcur[t] = excl;
  if (v > 0) gbase[t] = atomicAdd(&ccursor[t], v);
  __syncthreads();

  for (int i = t; i < cnt; i += 256) {
    int d = dst[e0 + i], s = src[e0 + i];
    int b = d >> 8;
    int p = atomicAdd(&lcur[b], 1);
    stage[p] = ((unsigned)b << 24) | ((unsigned)(d & 255) << 16) | (unsigned)s;
  }
  __syncthreads();

  for (int i = t; i < cnt; i += 256) {
    unsigned e = stage[i];
    int b = e >> 24;
    ebuf[gbase[b] + (i - scn[b])] = e;
  }
}

// ---------- D: per-bucket counting sort; edge_src emitted as ushort ----------
__global__ __launch_bounds__(256) void bucket_sort(
    const unsigned* __restrict__ ebuf, const int* __restrict__ cstart,
    unsigned short* __restrict__ edge_src, int* __restrict__ row_start,
    int* __restrict__ deg) {
  __shared__ int lhist[256], lscan[256], lcur[256];
  __shared__ unsigned short srt[CAP2];       // 16 KB
  int b = blockIdx.x, t = threadIdx.x;
  int s0 = cstart[b], s1 = cstart[b + 1];
  int cnt = s1 - s0;

  lhist[t] = 0; __syncthreads();
  for (int i = t; i < cnt; i += 256) atomicAdd(&lhist[(ebuf[s0 + i] >> 16) & 255], 1);
  __syncthreads();

  int v = lhist[t];
  lscan[t] = v; __syncthreads();
  for (int off = 1; off < 256; off <<= 1) {
    int a = (t >= off) ? lscan[t - off] : 0;
    __syncthreads();
    lscan[t] += a;
    __syncthreads();
  }
  lscan[t] -= v;
  lcur[t] = lscan[t];
  __syncthreads();

  for (int i = t; i < cnt; i += 256) {
    unsigned e = ebuf[s0 + i];
    int p = atomicAdd(&lcur[(e >> 16) & 255], 1);
    srt[p] = (unsigned short)(e & 0xFFFFu);
  }
  __syncthreads();

  for (int i = t; i < cnt; i += 256) edge_src[s0 + i] = srt[i];  // coalesced 2B

  int n = b * 256 + t;
  if (n < N_NODES) { row_start[n] = s0 + lscan[t]; deg[n] = v; }
}

// ---------- pull-mode mean aggregation over f16 rows ----------
// One wave per node: 8 edge-groups x 8 lanes; lane loads half8 (16 B) -> full
// 128 B row per group, 8 edges in flight per iteration. xor-fold(8,16,32);
// lanes 0-7 write the f32 mean row (256 B coalesced).
__global__ __launch_bounds__(256) void sage_aggregate16(
    const half8*          __restrict__ feat16,    // [N,8] half8 view of [N,64] f16
    const int*            __restrict__ row_start,
    const int*            __restrict__ deg,
    const unsigned short* __restrict__ edge_src,  // [E] sorted by dst
    float4*               __restrict__ mean4) {   // [N,16] float4 view
  int idx  = blockIdx.x * blockDim.x + threadIdx.x;
  int n    = idx >> 6;
  int lane = idx & 63;
  if (n >= N_NODES) return;
  int g = lane >> 3;     // edge sub-slot 0..7
  int q = lane & 7;      // feature octet 0..7
  int start = row_start[n];
  int d     = deg[n];
  float a0=0.f,a1=0.f,a2=0.f,a3=0.f,a4=0.f,a5=0.f,a6=0.f,a7=0.f;
  #pragma unroll 2
  for (int base = 0; base < d; base += 8) {
    int e = base + g;
    if (e < d) {
      int s = (int)edge_src[start + e];            // 8 lanes share one addr
      half8 v = feat16[(size_t)s * 8 + q];         // 128 B coalesced row gather
      a0 += (float)v[0]; a1 += (float)v[1]; a2 += (float)v[2]; a3 += (float)v[3];
      a4 += (float)v[4]; a5 += (float)v[5]; a6 += (float)v[6]; a7 += (float)v[7];
    }
  }
  #pragma unroll
  for (int off = 8; off < 64; off <<= 1) {
    a0 += __shfl_xor(a0, off); a1 += __shfl_xor(a1, off);
    a2 += __shfl_xor(a2, off); a3 += __shfl_xor(a3, off);
    a4 += __shfl_xor(a4, off); a5 += __shfl_xor(a5, off);
    a6 += __shfl_xor(a6, off); a7 += __shfl_xor(a7, off);
  }
  if (lane < 8) {
    float inv = (d > 0) ? 1.0f / (float)d : 0.0f;
    mean4[(size_t)n * 16 + lane * 2]     = make_float4(a0*inv, a1*inv, a2*inv, a3*inv);
    mean4[(size_t)n * 16 + lane * 2 + 1] = make_float4(a4*inv, a5*inv, a6*inv, a7*inv);
  }
}

// ---------- linear via scalar row reads (R7 proven) ----------
// Optionally emits an f16 copy of the output (for next layer's gather).
__global__ __launch_bounds__(256) void sage_linear(
    const float* __restrict__ xin,   // [N,64]
    const float* __restrict__ mean,  // [N,64]
    const float* __restrict__ W,     // [128,64] row-major
    const float* __restrict__ bias,  // [64]
    float*       __restrict__ out,   // [N,64]
    unsigned short* __restrict__ out16,   // [N,64] f16 copy, may be null
    int do_relu) {
  __shared__ float Ws[128 * 64];     // 32 KB
  int t = threadIdx.x;
  int j = t & 63;
  int g = __builtin_amdgcn_readfirstlane(t >> 6);   // wave id, forced SGPR

  {
    const float4* W4 = (const float4*)W;
    float4* Ws4 = (float4*)Ws;
    #pragma unroll
    for (int r = 0; r < 8; ++r) Ws4[r * 256 + t] = W4[r * 256 + t];
  }
  __syncthreads();

  int base = blockIdx.x * 32 + g * 8;               // uniform
  float bj = bias[j];
  float acc[8];
  #pragma unroll
  for (int u = 0; u < 8; ++u) acc[u] = bj;

  int nc[8];                                        // clamped node ids (uniform)
  #pragma unroll
  for (int u = 0; u < 8; ++u) {
    int n = base + u;
    nc[u] = (n < N_NODES) ? n : (N_NODES - 1);
  }

  #pragma unroll 8
  for (int k = 0; k < 64; ++k) {
    float w = Ws[k * 64 + j];
    #pragma unroll
    for (int u = 0; u < 8; ++u)
      acc[u] += xin[(size_t)nc[u] * 64 + k] * w;    // uniform addr -> s_load
  }
  #pragma unroll 8
  for (int k = 0; k < 64; ++k) {
    float w = Ws[(64 + k) * 64 + j];
    #pragma unroll
    for (int u = 0; u < 8; ++u)
      acc[u] += mean[(size_t)nc[u] * 64 + k] * w;   // uniform addr -> s_load
  }

  #pragma unroll
  for (int u = 0; u < 8; ++u) {
    int n = base + u;
    if (n < N_NODES) {
      float v = acc[u];
      if (do_relu) v = fmaxf(v, 0.0f);
      out[(size_t)n * 64 + j] = v;
      if (out16 != nullptr) {
        _Float16 hv = (_Float16)v;
        out16[(size_t)n * 64 + j] = *(unsigned short*)&hv;
      }
    }
  }
}

extern "C" void kernel_launch(void* const* d_in, const int* in_sizes, int n_in,
                              void* d_out, int out_size, void* d_ws, size_t ws_size,
                              hipStream_t stream) {
  const float* x  = (const float*)d_in[0];
  const int*   ei = (const int*)d_in[1];   // [2,E]: row 0 = src, row 1 = dst
  const float* W1 = (const float*)d_in[2];
  const float* b1 = (const float*)d_in[3];
  const float* W2 = (const float*)d_in[4];
  const float* b2 = (const float*)d_in[5];
  float* out = (float*)d_out;

  const int* src = ei;
  const int* dst = ei + N_EDGES;

  // ws layout (int offsets), all 16B-aligned:
  //   ccount@0[256] | cstart@512[260] | ccursor@1024[256] | deg@1536[50048] |
  //   row_start@51584[50048] | edge_src16@101632[400000] | ebuf@501632[800000] |
  //   mean@1301632[3200000] | h1@4501632[3200000] | x16@7701632[1600000] |
  //   h116@9301632[1600000]  -> total 10,901,632 ints = 43.6 MB
  int* wsi       = (int*)d_ws;
  int* ccount    = wsi;
  int* cstart    = wsi + 512;
  int* ccursor   = wsi + 1024;
  int* deg       = wsi + 1536;
  int* row_start = wsi + 51584;
  unsigned short* edge_src = (unsigned short*)(wsi + 101632);
  unsigned* ebuf = (unsigned*)(wsi + 501632);
  float* mean    = (float*)(wsi + 1301632);
  float* h1      = (float*)(wsi + 4501632);
  half8* x16     = (half8*)(wsi + 7701632);
  unsigned short* h116 = (unsigned short*)(wsi + 9301632);

  hipMemsetAsync(ccount, 0, 256 * sizeof(int), stream);

  dim3 blk(256);
  to_f16<<<(N_NODES * F / 8 + 255) / 256, blk, 0, stream>>>((const float4*)x, x16);
  coarse_hist<<<256, blk, 0, stream>>>(dst, ccount);
  coarse_scan<<<1, blk, 0, stream>>>(ccount, cstart, ccursor);
  partition_coarse<<<NWG1, blk, 0, stream>>>(src, dst, ccursor, ebuf);
  bucket_sort<<<NBUCK, blk, 0, stream>>>(ebuf, cstart, edge_src, row_start, deg);

  dim3 grd_agg((unsigned)(((size_t)N_NODES * 64 + 255) / 256));  // 12500
  dim3 grd_lin((N_NODES + 31) / 32);                             // 1563

  // Layer 1
  sage_aggregate16<<<grd_agg, blk, 0, stream>>>(
      x16, row_start, deg, edge_src, (float4*)mean);
  sage_linear<<<grd_lin, blk, 0, stream>>>(x, mean, W1, b1, h1, h116, 1);
  // Layer 2
  sage_aggregate16<<<grd_agg, blk, 0, stream>>>(
      (const half8*)h116, row_start, deg, edge_src, (float4*)mean);
  sage_linear<<<grd_lin, blk, 0, stream>>>(h1, mean, W2, b2, out, nullptr, 0);
}